// Round 7
// baseline (213.382 us; speedup 1.0000x reference)
//
#include <hip/hip_runtime.h>
#include <math.h>

#define BATCH 16
#define NTOK 1024
#define HEADS 8
#define DHEAD 64
#define INNER 512
#define QKV_COLS 1536
// 0.125 * log2(e): p = exp2(qk*SCALE_L2E + bias*log2e)
#define SCALE_L2E 0.1803368801111244f
#define LOG2E 1.4426950408889634f

#if __has_builtin(__builtin_amdgcn_exp2f)
#define EXP2F(x) __builtin_amdgcn_exp2f(x)
#else
#define EXP2F(x) __expf((x) * 0.6931471805599453f)
#endif

typedef _Float16 f16x8 __attribute__((ext_vector_type(8)));
typedef _Float16 f16x4 __attribute__((ext_vector_type(4)));
typedef float f32x4 __attribute__((ext_vector_type(4)));

#define MFMA32(a, b, c) __builtin_amdgcn_mfma_f32_16x16x32_f16(a, b, c, 0, 0, 0)

// async global->LDS, 16B per lane. LDS dest is wave-uniform base + lane*16.
__device__ __forceinline__ void glds16(const void* g, void* l) {
    __builtin_amdgcn_global_load_lds(
        (const __attribute__((address_space(1))) unsigned int*)g,
        (__attribute__((address_space(3))) unsigned int*)l, 16, 0, 0);
}

// ---------------------------------------------------------------------------
// W transposes only (x-conversion is fused into the QKV GEMM now).
// Wq_t[n][k] = Wq[k][n]; Wo_t[n][k] = Wo[k][n].
// ---------------------------------------------------------------------------
#define WQ (INNER * QKV_COLS)                // 786432
#define WO (INNER * INNER)                   // 262144

__global__ __launch_bounds__(256)
void convert_w(const float* __restrict__ Wq, const float* __restrict__ Wo,
               _Float16* __restrict__ Wq_t, _Float16* __restrict__ Wo_t) {
    int idx = blockIdx.x * 256 + threadIdx.x;
    if (idx < WQ) {
        int n = idx >> 9, k = idx & 511;
        Wq_t[idx] = (_Float16)Wq[k * QKV_COLS + n];
    } else if (idx < WQ + WO) {
        int i = idx - WQ;
        int n = i >> 9, k = i & 511;
        Wo_t[i] = (_Float16)Wo[k * INNER + n];
    }
}

// ---------------------------------------------------------------------------
// f16 MFMA GEMM v4: C[M,N] = A[M,K] @ Bt[N,K]^T.
// Structure = v3 (double-buffered BK=32, one barrier/step, stage(k+1) under
// compute(k), bijective XCD swizzle, XOR-swizzled LDS, C^T epilogue).
// NEW (MODE==2): A is the f32 activation read DIRECTLY (reg-staged:
// global_load_dwordx4 -> cvt f16 -> swizzled ds_write_b128), fusing the old
// convert_inputs x-pass into the GEMM: -48 MB HBM + one kernel. Loads for
// step k+1 issue right after the barrier; the ds_write lands after compute
// (T14 issue-early/write-late: HBM latency hides under the MFMA phase).
// ds_write bank check: 64 lanes -> 8 words/bank (b128 minimum, conflict-free).
// MODE: 0 = A f16 (glds16 path), f32 out + bias.
//       2 = A f32 (reg-staged), f16 out, V col-blocks direct to vt layout.
// ---------------------------------------------------------------------------
template<int MODE>
__global__ __launch_bounds__(256, 4)
void gemm_f16(const _Float16* __restrict__ A, const float* __restrict__ Af,
              const _Float16* __restrict__ Bt, const float* __restrict__ bias,
              void* __restrict__ Cout, _Float16* __restrict__ vtg,
              int M, int N, int K) {
    __shared__ _Float16 As[2][128 * 32];   // 8 KB per buffer
    __shared__ _Float16 Bs[2][128 * 32];

    const int t    = threadIdx.x;
    const int l    = t & 63;
    const int w    = t >> 6;
    const int wm   = w >> 1;
    const int wn   = w & 1;
    const int quad = l >> 4;
    const int lrow = l & 15;

    // bijective XCD swizzle (requires nwg % 8 == 0; 1536 and 512 both are)
    const int nwg = gridDim.x * gridDim.y;
    int bid = blockIdx.x + gridDim.x * blockIdx.y;
    bid = (bid & 7) * (nwg >> 3) + (bid >> 3);
    const size_t row0 = (size_t)(bid / gridDim.x) * 128;
    const size_t col0 = (size_t)(bid % gridDim.x) * 128;

    const int srow = t >> 2;    // staging row 0..63 (2 passes of 64)
    const int sch  = t & 3;     // chunk 0..3 (8 f16 / 8 f32 each)

    f32x4 acc[4][4] = {};
    const int NSTEP = K >> 5;   // 16

    float4 ar[2][2];            // MODE==2: in-flight f32 A rows (2 rows x 8 f32)

    auto loadA = [&](int kk, int bufi) {
        if (MODE == 2) {
#pragma unroll
            for (int p = 0; p < 2; ++p) {
                const float* s = Af + (row0 + p * 64 + srow) * K + kk * 32 + sch * 8;
                ar[p][0] = *(const float4*)s;
                ar[p][1] = *(const float4*)(s + 4);
            }
        } else {
#pragma unroll
            for (int p = 0; p < 2; ++p) {
                const int r  = p * 64 + srow;
                const int gc = (sch ^ (r & 3)) * 8;     // pre-swizzled source col
                glds16(A + (row0 + r) * K + kk * 32 + gc,
                       (char*)As[bufi] + p * 4096 + t * 16);
            }
        }
    };
    auto writeA = [&](int bufi) {           // MODE==2 only: cvt + swizzled write
#pragma unroll
        for (int p = 0; p < 2; ++p) {
            const int r = p * 64 + srow;
            f16x8 h;
#pragma unroll
            for (int e = 0; e < 4; ++e) {
                h[e]     = (_Float16)ar[p][0][e];
                h[4 + e] = (_Float16)ar[p][1][e];
            }
            *(f16x8*)(As[bufi] + r * 32 + ((sch ^ (r & 3)) * 8)) = h;
        }
    };
    auto stageB = [&](int kk, int bufi) {
#pragma unroll
        for (int p = 0; p < 2; ++p) {
            const int r  = p * 64 + srow;
            const int gc = (sch ^ (r & 3)) * 8;
            glds16(Bt + (col0 + r) * K + kk * 32 + gc,
                   (char*)Bs[bufi] + p * 4096 + t * 16);
        }
    };

    // prologue: tile 0
    loadA(0, 0);
    stageB(0, 0);
    if (MODE == 2) writeA(0);

    for (int kk = 0; kk < NSTEP; ++kk) {
        const int buf = kk & 1;
        __syncthreads();                 // buf staged; prev compute done
        if (kk + 1 < NSTEP) { stageB(kk + 1, buf ^ 1); loadA(kk + 1, buf ^ 1); }

        f16x8 af[4], bf[4];
#pragma unroll
        for (int i = 0; i < 4; ++i) {
            const int r = wm * 64 + i * 16 + lrow;
            af[i] = *(const f16x8*)(As[buf] + r * 32 + ((quad ^ (r & 3)) * 8));
        }
#pragma unroll
        for (int j = 0; j < 4; ++j) {
            const int r = wn * 64 + j * 16 + lrow;
            bf[j] = *(const f16x8*)(Bs[buf] + r * 32 + ((quad ^ (r & 3)) * 8));
        }
#pragma unroll
        for (int i = 0; i < 4; ++i)
#pragma unroll
            for (int j = 0; j < 4; ++j)
                acc[i][j] = MFMA32(bf[j], af[i], acc[i][j]);   // C^T fragment

        if (MODE == 2 && kk + 1 < NSTEP) writeA(buf ^ 1);      // write-late
    }

    // Epilogue: lane holds C[m][c..c+3], m = row0+wm*64+i*16+lrow,
    //           c = col0+wn*64+j*16+quad*4.
    const bool isV = (MODE == 2) && (col0 >= 2 * INNER);
#pragma unroll
    for (int i = 0; i < 4; ++i) {
        const size_t m = row0 + wm * 64 + i * 16 + lrow;
#pragma unroll
        for (int j = 0; j < 4; ++j) {
            const size_t c = col0 + wn * 64 + j * 16 + quad * 4;
            f32x4 v = acc[i][j];
            if (MODE == 0) {
                float4 bv = *(const float4*)(bias + c);
                v[0] += bv.x; v[1] += bv.y; v[2] += bv.z; v[3] += bv.w;
                *(f32x4*)((float*)Cout + m * N + c) = v;
            } else if (!isV) {
                f16x4 hv;
                hv[0] = (_Float16)v[0]; hv[1] = (_Float16)v[1];
                hv[2] = (_Float16)v[2]; hv[3] = (_Float16)v[3];
                *(f16x4*)((_Float16*)Cout + m * N + c) = hv;
            } else {
                // V columns -> vt[b][h][d][n]; d = j*16+quad*4+reg, n = m&1023
                const int cv = (int)(c - 2 * INNER);        // 0..511
                const int hh = cv >> 6, db = cv & 63;
                const size_t vb = (((size_t)(m >> 10) * HEADS + hh) * 64 + db) * NTOK
                                  + (m & (NTOK - 1));
#pragma unroll
                for (int reg = 0; reg < 4; ++reg)
                    vtg[vb + (size_t)reg * NTOK] = (_Float16)v[reg];
            }
        }
    }
}

// ---------------------------------------------------------------------------
// Flash attention v7 = v6 (57.4 us, 0 conflicts) + T5 setprio around MFMA
// clusters (m191: +4-7% on attn, within-probe verified; not applied to the
// lockstep GEMM per m190).
// ---------------------------------------------------------------------------
__global__ __launch_bounds__(512, 4)
void attn_f16_v7(const _Float16* __restrict__ qkv, const _Float16* __restrict__ vt,
                 const float* __restrict__ rel_table, _Float16* __restrict__ out) {
    __shared__ _Float16 Ks[2][64 * 64];   // [key][d], fK-swizzled 16B chunks
    __shared__ _Float16 Vs[2][64 * 64];   // [d][j], (row&7)-swizzled 16B chunks
    __shared__ float biasS[3969];         // this head's bias column * log2e

    const int t    = threadIdx.x;
    const int l    = t & 63;
    const int w    = t >> 6;              // 0..7
    const int quad = l >> 4;
    const int lrow = l & 15;
    const int h    = blockIdx.y;
    const int bb   = blockIdx.z;
    const int qr0  = blockIdx.x * 256 + w * 32;   // this wave's 32 query rows

    for (int idx = t; idx < 3969; idx += 512)
        biasS[idx] = rel_table[idx * HEADS + h] * LOG2E;

    const size_t tokbase = (size_t)bb * NTOK;

    // Q fragments: Q[qr0 + mt*16 + lrow][ksi*32 + quad*8 + e].
    f16x8 aq[2][2];
#pragma unroll
    for (int mt = 0; mt < 2; ++mt)
#pragma unroll
        for (int ksi = 0; ksi < 2; ++ksi)
            aq[mt][ksi] = *(const f16x8*)(qkv + (tokbase + qr0 + mt * 16 + lrow) * QKV_COLS
                                          + h * DHEAD + ksi * 32 + quad * 8);

    // O^T accumulators: O[mt][dn] lane holds out[m=lrow][d=dn*16+quad*4+reg]
    f32x4 O[2][4] = {};
    float l0 = 0.f, l1 = 0.f;

    const int iy = qr0 >> 5;                               // wave-constant
    const int krow_base = 8 * (lrow >> 2) + (lrow & 3);
    const int fKl = (lrow & 3) + 4 * ((lrow >> 2) & 1);

    const int kr  = t >> 3;     // staging row 0..63
    const int ksl = t & 7;      // LDS chunk slot
    const int fKr = (kr & 3) + 4 * ((kr >> 3) & 1);
    const _Float16* kbase = qkv + tokbase * QKV_COLS + INNER + h * DHEAD;
    const _Float16* vbase = vt + ((size_t)(bb * HEADS + h) * 64) * NTOK;

    auto stage = [&](int jt, int bufi) {
        const int j0s = jt * 64;
        glds16(kbase + (size_t)(j0s + kr) * QKV_COLS + (ksl ^ fKr) * 8, (char*)Ks[bufi] + t * 16);
        glds16(vbase + (size_t)kr * NTOK + j0s + (ksl ^ (kr & 7)) * 8,  (char*)Vs[bufi] + t * 16);
    };

    stage(0, 0);

    for (int jt = 0; jt < 16; ++jt) {
        const int buf = jt & 1;
        __syncthreads();                 // staged tile jt ready; prev compute done
        if (jt < 15) stage(jt + 1, buf ^ 1);

#pragma unroll
        for (int jn0 = 0; jn0 < 2; ++jn0) {
            f16x8 pb0, pb1;              // PV B-fragments (built across s=0,1)
#pragma unroll
            for (int s = 0; s < 2; ++s) {
                // --- S^T = K Q^T on permuted K rows ---
                const int krow = jn0 * 32 + krow_base + 4 * s;
                f32x4 S0 = {}, S1 = {};
                __builtin_amdgcn_s_setprio(1);
#pragma unroll
                for (int ksi = 0; ksi < 2; ++ksi) {
                    f16x8 bk = *(const f16x8*)(Ks[buf] + krow * 64
                                               + (((ksi * 4 + quad) ^ fKl) * 8));
                    S0 = MFMA32(bk, aq[0][ksi], S0);   // P^T for keys 8q+4s+reg
                    S1 = MFMA32(bk, aq[1][ksi], S1);
                }
                __builtin_amdgcn_s_setprio(0);
                // bias idx = (iy-jy+31)*63 + 31 + ix - jx
                const int base = (iy - (jt * 2 + jn0) + 31) * 63 + 31 + lrow
                                 - 8 * quad - 4 * s;
                {   // mt = 0
                    float p0 = EXP2F(fmaf(S0[0], SCALE_L2E, biasS[base - 0]));
                    float p1 = EXP2F(fmaf(S0[1], SCALE_L2E, biasS[base - 1]));
                    float p2 = EXP2F(fmaf(S0[2], SCALE_L2E, biasS[base - 2]));
                    float p3 = EXP2F(fmaf(S0[3], SCALE_L2E, biasS[base - 3]));
                    l0 += (p0 + p1) + (p2 + p3);
                    pb0[s * 4 + 0] = (_Float16)p0; pb0[s * 4 + 1] = (_Float16)p1;
                    pb0[s * 4 + 2] = (_Float16)p2; pb0[s * 4 + 3] = (_Float16)p3;
                }
                {   // mt = 1
                    const int b1 = base + 16;
                    float p0 = EXP2F(fmaf(S1[0], SCALE_L2E, biasS[b1 - 0]));
                    float p1 = EXP2F(fmaf(S1[1], SCALE_L2E, biasS[b1 - 1]));
                    float p2 = EXP2F(fmaf(S1[2], SCALE_L2E, biasS[b1 - 2]));
                    float p3 = EXP2F(fmaf(S1[3], SCALE_L2E, biasS[b1 - 3]));
                    l1 += (p0 + p1) + (p2 + p3);
                    pb1[s * 4 + 0] = (_Float16)p0; pb1[s * 4 + 1] = (_Float16)p1;
                    pb1[s * 4 + 2] = (_Float16)p2; pb1[s * 4 + 3] = (_Float16)p3;
                }
            }

            // --- O^T += V^T P^T : K=32 MFMA, V rows d, keys jn0*32+quad*8+e ---
            __builtin_amdgcn_s_setprio(1);
#pragma unroll
            for (int dn = 0; dn < 4; ++dn) {
                const int d = dn * 16 + lrow;
                f16x8 av = *(const f16x8*)(Vs[buf] + d * 64
                              + (((jn0 * 4 + quad) ^ (d & 7)) * 8));
                O[0][dn] = MFMA32(av, pb0, O[0][dn]);
                O[1][dn] = MFMA32(av, pb1, O[1][dn]);
            }
            __builtin_amdgcn_s_setprio(0);
        }
    }

    // --- l reduction: lanes {m, m+16, m+32, m+48} hold quad-partials of row m ---
#pragma unroll
    for (int mt = 0; mt < 2; ++mt) {
        float s = mt ? l1 : l0;
        s += __shfl_xor(s, 16);
        s += __shfl_xor(s, 32);
        const float inv = 1.f / s;
        const size_t orow = (tokbase + qr0 + mt * 16 + lrow) * INNER + h * DHEAD;
#pragma unroll
        for (int dn = 0; dn < 4; ++dn) {
            const f32x4 o = O[mt][dn];
            f16x4 ov;
            ov[0] = (_Float16)(o[0] * inv); ov[1] = (_Float16)(o[1] * inv);
            ov[2] = (_Float16)(o[2] * inv); ov[3] = (_Float16)(o[3] * inv);
            *(f16x4*)(out + orow + dn * 16 + quad * 4) = ov;
        }
    }
}

// ---------------------------------------------------------------------------
extern "C" void kernel_launch(void* const* d_in, const int* in_sizes, int n_in,
                              void* d_out, int out_size, void* d_ws, size_t ws_size,
                              hipStream_t stream) {
    const float* x         = (const float*)d_in[0];
    const float* W_qkv     = (const float*)d_in[1];
    const float* rel_table = (const float*)d_in[2];
    const float* W_out     = (const float*)d_in[3];
    const float* b_out     = (const float*)d_in[4];

    _Float16* Wq_t  = (_Float16*)d_ws;                        // 786,432
    _Float16* Wo_t  = Wq_t + (size_t)INNER * QKV_COLS;        // 262,144
    _Float16* qkv_h = Wo_t + (size_t)INNER * INNER;           // 25,165,824
    _Float16* att_h = qkv_h + (size_t)BATCH * NTOK * QKV_COLS;// 8,388,608
    _Float16* vt_g  = att_h + (size_t)BATCH * NTOK * INNER;   // 8,388,608

    const int M = BATCH * NTOK;  // 16384

    convert_w<<<(WQ + WO + 255) / 256, 256, 0, stream>>>(W_qkv, W_out, Wq_t, Wo_t);

    // QKV GEMM; A = f32 x read directly (conversion fused); V -> vt layout.
    gemm_f16<2><<<dim3(QKV_COLS / 128, M / 128), 256, 0, stream>>>(
        nullptr, x, Wq_t, nullptr, qkv_h, vt_g, M, QKV_COLS, INNER);

    attn_f16_v7<<<dim3(NTOK / 256, HEADS, BATCH), 512, 0, stream>>>(
        qkv_h, vt_g, rel_table, att_h);

    gemm_f16<0><<<dim3(INNER / 128, M / 128), 256, 0, stream>>>(
        att_h, nullptr, Wo_t, b_out, d_out, nullptr, M, INNER, INNER);
}

// Round 8
// 205.638 us; speedup vs baseline: 1.0377x; 1.0377x over previous
//
#include <hip/hip_runtime.h>
#include <math.h>

#define BATCH 16
#define NTOK 1024
#define HEADS 8
#define DHEAD 64
#define INNER 512
#define QKV_COLS 1536
// 0.125 * log2(e): p = exp2(qk*SCALE_L2E + bias*log2e)
#define SCALE_L2E 0.1803368801111244f
#define LOG2E 1.4426950408889634f

#if __has_builtin(__builtin_amdgcn_exp2f)
#define EXP2F(x) __builtin_amdgcn_exp2f(x)
#else
#define EXP2F(x) __expf((x) * 0.6931471805599453f)
#endif

typedef _Float16 f16x8 __attribute__((ext_vector_type(8)));
typedef _Float16 f16x4 __attribute__((ext_vector_type(4)));
typedef float f32x4 __attribute__((ext_vector_type(4)));

#define MFMA32(a, b, c) __builtin_amdgcn_mfma_f32_16x16x32_f16(a, b, c, 0, 0, 0)

// async global->LDS, 16B per lane. LDS dest is wave-uniform base + lane*16.
__device__ __forceinline__ void glds16(const void* g, void* l) {
    __builtin_amdgcn_global_load_lds(
        (const __attribute__((address_space(1))) unsigned int*)g,
        (__attribute__((address_space(3))) unsigned int*)l, 16, 0, 0);
}

// ---------------------------------------------------------------------------
// Input conversion: x -> f16; W_qkv, W_out -> transposed f16 (Bt[n][k]).
// ---------------------------------------------------------------------------
#define XV (BATCH * NTOK * INNER / 4)        // 2097152 float4 groups
#define WQ (INNER * QKV_COLS)                // 786432
#define WO (INNER * INNER)                   // 262144

__global__ __launch_bounds__(256)
void convert_inputs(const float* __restrict__ x, const float* __restrict__ Wq,
                    const float* __restrict__ Wo, _Float16* __restrict__ x_h,
                    _Float16* __restrict__ Wq_t, _Float16* __restrict__ Wo_t) {
    int idx = blockIdx.x * 256 + threadIdx.x;
    if (idx < XV) {
        float4 v = ((const float4*)x)[idx];
        f16x4 h;
        h[0] = (_Float16)v.x; h[1] = (_Float16)v.y;
        h[2] = (_Float16)v.z; h[3] = (_Float16)v.w;
        *(f16x4*)(x_h + (size_t)idx * 4) = h;
    } else if (idx < XV + WQ) {
        int i = idx - XV;
        int n = i >> 9, k = i & 511;                 // Wq_t[n][k] = Wq[k][n]
        Wq_t[i] = (_Float16)Wq[k * QKV_COLS + n];
    } else if (idx < XV + WQ + WO) {
        int i = idx - XV - WQ;
        int n = i >> 9, k = i & 511;
        Wo_t[i] = (_Float16)Wo[k * INNER + n];
    }
}

// ---------------------------------------------------------------------------
// f16 MFMA GEMM v5: C[M,N] = A[M,K] @ Bt[N,K]^T.
// Round-7 post-mortem fixes:
//  (1) swizzle g(r)=r&3 on 64B rows was a 4-WAY BANK CONFLICT on every
//      ds_read_b128 (measured 3.1M cycles): even rows hit only 2 of 4 slot
//      values. Correct function for 64B rows: g(r)=(r>>1)&3 -> each 4-bank
//      group hit exactly 2x per quarter-wave (the free minimum).
//  (2) reg-staged f32 A serialized each step on HBM latency -> back to pure
//      glds16 f16 staging (x pre-converted by convert_inputs).
//  (3) T4 counted-vmcnt pipeline: 3 LDS buffers (48KB -> 3 blocks/CU),
//      2-tiles-ahead prefetch, raw s_barrier + asm vmcnt(4) -> tile k+1's
//      loads stay in flight ACROSS the barrier (never drain to 0 in-loop).
//      Buffer-reuse audit: stage(k+2) overwrites the buffer computed at k-1;
//      every wave passed barrier(k) only after its MFMAs consumed those
//      ds_reads -> safe. sched_barrier(0) pins glds16/ds_read order.
// MODE: 0 = f32 out + bias; 2 = f16 out, V col-blocks direct to vt layout.
// ---------------------------------------------------------------------------
template<int MODE>
__global__ __launch_bounds__(256, 3)
void gemm_f16(const _Float16* __restrict__ A, const _Float16* __restrict__ Bt,
              const float* __restrict__ bias, void* __restrict__ Cout,
              _Float16* __restrict__ vtg, int M, int N, int K) {
    __shared__ _Float16 As[3][128 * 32];   // 8 KB per buffer
    __shared__ _Float16 Bs[3][128 * 32];

    const int t    = threadIdx.x;
    const int l    = t & 63;
    const int w    = t >> 6;
    const int wm   = w >> 1;
    const int wn   = w & 1;
    const int quad = l >> 4;
    const int lrow = l & 15;

    // bijective XCD swizzle (requires nwg % 8 == 0; 1536 and 512 both are)
    const int nwg = gridDim.x * gridDim.y;
    int bid = blockIdx.x + gridDim.x * blockIdx.y;
    bid = (bid & 7) * (nwg >> 3) + (bid >> 3);
    const size_t row0 = (size_t)(bid / gridDim.x) * 128;
    const size_t col0 = (size_t)(bid % gridDim.x) * 128;

    const int srow = t >> 2;    // staging row 0..63 (2 passes of 64)
    const int sch  = t & 3;     // LDS chunk slot; holds global chunk sch^g(row)

    f32x4 acc[4][4] = {};
    const int NSTEP = K >> 5;   // 16

    auto stage = [&](int kk, int bufi) {
#pragma unroll
        for (int p = 0; p < 2; ++p) {
            const int r  = p * 64 + srow;
            const int gc = (sch ^ ((r >> 1) & 3)) * 8;   // pre-swizzled source
            glds16(A  + (row0 + r) * K + kk * 32 + gc, (char*)As[bufi] + p * 4096 + t * 16);
            glds16(Bt + (col0 + r) * K + kk * 32 + gc, (char*)Bs[bufi] + p * 4096 + t * 16);
        }
    };

    stage(0, 0);
    stage(1, 1);

    int buf = 0, pre = 2;                   // rolling kk%3 and (kk+2)%3
    for (int kk = 0; kk < NSTEP; ++kk) {
        // wait for tile kk's 4 loads only; tile kk+1's 4 stay in flight
        if (kk + 1 < NSTEP) asm volatile("s_waitcnt vmcnt(4)" ::: "memory");
        else                asm volatile("s_waitcnt vmcnt(0)" ::: "memory");
        __builtin_amdgcn_s_barrier();
        __builtin_amdgcn_sched_barrier(0);
        if (kk + 2 < NSTEP) stage(kk + 2, pre);

        f16x8 af[4], bf[4];
#pragma unroll
        for (int i = 0; i < 4; ++i) {
            const int r = wm * 64 + i * 16 + lrow;
            af[i] = *(const f16x8*)(As[buf] + r * 32 + ((quad ^ ((r >> 1) & 3)) * 8));
        }
#pragma unroll
        for (int j = 0; j < 4; ++j) {
            const int r = wn * 64 + j * 16 + lrow;
            bf[j] = *(const f16x8*)(Bs[buf] + r * 32 + ((quad ^ ((r >> 1) & 3)) * 8));
        }
#pragma unroll
        for (int i = 0; i < 4; ++i)
#pragma unroll
            for (int j = 0; j < 4; ++j)
                acc[i][j] = MFMA32(bf[j], af[i], acc[i][j]);   // C^T fragment

        buf = (buf == 2) ? 0 : buf + 1;
        pre = (pre == 2) ? 0 : pre + 1;
    }

    // Epilogue: lane holds C[m][c..c+3], m = row0+wm*64+i*16+lrow,
    //           c = col0+wn*64+j*16+quad*4.
    const bool isV = (MODE == 2) && (col0 >= 2 * INNER);
#pragma unroll
    for (int i = 0; i < 4; ++i) {
        const size_t m = row0 + wm * 64 + i * 16 + lrow;
#pragma unroll
        for (int j = 0; j < 4; ++j) {
            const size_t c = col0 + wn * 64 + j * 16 + quad * 4;
            f32x4 v = acc[i][j];
            if (MODE == 0) {
                float4 bv = *(const float4*)(bias + c);
                v[0] += bv.x; v[1] += bv.y; v[2] += bv.z; v[3] += bv.w;
                *(f32x4*)((float*)Cout + m * N + c) = v;
            } else if (!isV) {
                f16x4 hv;
                hv[0] = (_Float16)v[0]; hv[1] = (_Float16)v[1];
                hv[2] = (_Float16)v[2]; hv[3] = (_Float16)v[3];
                *(f16x4*)((_Float16*)Cout + m * N + c) = hv;
            } else {
                // V columns -> vt[b][h][d][n]; d = j*16+quad*4+reg, n = m&1023
                const int cv = (int)(c - 2 * INNER);        // 0..511
                const int hh = cv >> 6, db = cv & 63;
                const size_t vb = (((size_t)(m >> 10) * HEADS + hh) * 64 + db) * NTOK
                                  + (m & (NTOK - 1));
#pragma unroll
                for (int reg = 0; reg < 4; ++reg)
                    vtg[vb + (size_t)reg * NTOK] = (_Float16)v[reg];
            }
        }
    }
}

// ---------------------------------------------------------------------------
// Flash attention v7 = v6 (57.4 us, 0 conflicts) + T5 setprio around MFMA
// clusters. (unchanged from round 7)
// ---------------------------------------------------------------------------
__global__ __launch_bounds__(512, 4)
void attn_f16_v7(const _Float16* __restrict__ qkv, const _Float16* __restrict__ vt,
                 const float* __restrict__ rel_table, _Float16* __restrict__ out) {
    __shared__ _Float16 Ks[2][64 * 64];   // [key][d], fK-swizzled 16B chunks
    __shared__ _Float16 Vs[2][64 * 64];   // [d][j], (row&7)-swizzled 16B chunks
    __shared__ float biasS[3969];         // this head's bias column * log2e

    const int t    = threadIdx.x;
    const int l    = t & 63;
    const int w    = t >> 6;              // 0..7
    const int quad = l >> 4;
    const int lrow = l & 15;
    const int h    = blockIdx.y;
    const int bb   = blockIdx.z;
    const int qr0  = blockIdx.x * 256 + w * 32;   // this wave's 32 query rows

    for (int idx = t; idx < 3969; idx += 512)
        biasS[idx] = rel_table[idx * HEADS + h] * LOG2E;

    const size_t tokbase = (size_t)bb * NTOK;

    // Q fragments: Q[qr0 + mt*16 + lrow][ksi*32 + quad*8 + e].
    f16x8 aq[2][2];
#pragma unroll
    for (int mt = 0; mt < 2; ++mt)
#pragma unroll
        for (int ksi = 0; ksi < 2; ++ksi)
            aq[mt][ksi] = *(const f16x8*)(qkv + (tokbase + qr0 + mt * 16 + lrow) * QKV_COLS
                                          + h * DHEAD + ksi * 32 + quad * 8);

    // O^T accumulators: O[mt][dn] lane holds out[m=lrow][d=dn*16+quad*4+reg]
    f32x4 O[2][4] = {};
    float l0 = 0.f, l1 = 0.f;

    const int iy = qr0 >> 5;                               // wave-constant
    const int krow_base = 8 * (lrow >> 2) + (lrow & 3);
    const int fKl = (lrow & 3) + 4 * ((lrow >> 2) & 1);

    const int kr  = t >> 3;     // staging row 0..63
    const int ksl = t & 7;      // LDS chunk slot
    const int fKr = (kr & 3) + 4 * ((kr >> 3) & 1);
    const _Float16* kbase = qkv + tokbase * QKV_COLS + INNER + h * DHEAD;
    const _Float16* vbase = vt + ((size_t)(bb * HEADS + h) * 64) * NTOK;

    auto stage = [&](int jt, int bufi) {
        const int j0s = jt * 64;
        glds16(kbase + (size_t)(j0s + kr) * QKV_COLS + (ksl ^ fKr) * 8, (char*)Ks[bufi] + t * 16);
        glds16(vbase + (size_t)kr * NTOK + j0s + (ksl ^ (kr & 7)) * 8,  (char*)Vs[bufi] + t * 16);
    };

    stage(0, 0);

    for (int jt = 0; jt < 16; ++jt) {
        const int buf = jt & 1;
        __syncthreads();                 // staged tile jt ready; prev compute done
        if (jt < 15) stage(jt + 1, buf ^ 1);

#pragma unroll
        for (int jn0 = 0; jn0 < 2; ++jn0) {
            f16x8 pb0, pb1;              // PV B-fragments (built across s=0,1)
#pragma unroll
            for (int s = 0; s < 2; ++s) {
                // --- S^T = K Q^T on permuted K rows ---
                const int krow = jn0 * 32 + krow_base + 4 * s;
                f32x4 S0 = {}, S1 = {};
                __builtin_amdgcn_s_setprio(1);
#pragma unroll
                for (int ksi = 0; ksi < 2; ++ksi) {
                    f16x8 bk = *(const f16x8*)(Ks[buf] + krow * 64
                                               + (((ksi * 4 + quad) ^ fKl) * 8));
                    S0 = MFMA32(bk, aq[0][ksi], S0);   // P^T for keys 8q+4s+reg
                    S1 = MFMA32(bk, aq[1][ksi], S1);
                }
                __builtin_amdgcn_s_setprio(0);
                // bias idx = (iy-jy+31)*63 + 31 + ix - jx
                const int base = (iy - (jt * 2 + jn0) + 31) * 63 + 31 + lrow
                                 - 8 * quad - 4 * s;
                {   // mt = 0
                    float p0 = EXP2F(fmaf(S0[0], SCALE_L2E, biasS[base - 0]));
                    float p1 = EXP2F(fmaf(S0[1], SCALE_L2E, biasS[base - 1]));
                    float p2 = EXP2F(fmaf(S0[2], SCALE_L2E, biasS[base - 2]));
                    float p3 = EXP2F(fmaf(S0[3], SCALE_L2E, biasS[base - 3]));
                    l0 += (p0 + p1) + (p2 + p3);
                    pb0[s * 4 + 0] = (_Float16)p0; pb0[s * 4 + 1] = (_Float16)p1;
                    pb0[s * 4 + 2] = (_Float16)p2; pb0[s * 4 + 3] = (_Float16)p3;
                }
                {   // mt = 1
                    const int b1 = base + 16;
                    float p0 = EXP2F(fmaf(S1[0], SCALE_L2E, biasS[b1 - 0]));
                    float p1 = EXP2F(fmaf(S1[1], SCALE_L2E, biasS[b1 - 1]));
                    float p2 = EXP2F(fmaf(S1[2], SCALE_L2E, biasS[b1 - 2]));
                    float p3 = EXP2F(fmaf(S1[3], SCALE_L2E, biasS[b1 - 3]));
                    l1 += (p0 + p1) + (p2 + p3);
                    pb1[s * 4 + 0] = (_Float16)p0; pb1[s * 4 + 1] = (_Float16)p1;
                    pb1[s * 4 + 2] = (_Float16)p2; pb1[s * 4 + 3] = (_Float16)p3;
                }
            }

            // --- O^T += V^T P^T : K=32 MFMA, V rows d, keys jn0*32+quad*8+e ---
            __builtin_amdgcn_s_setprio(1);
#pragma unroll
            for (int dn = 0; dn < 4; ++dn) {
                const int d = dn * 16 + lrow;
                f16x8 av = *(const f16x8*)(Vs[buf] + d * 64
                              + (((jn0 * 4 + quad) ^ (d & 7)) * 8));
                O[0][dn] = MFMA32(av, pb0, O[0][dn]);
                O[1][dn] = MFMA32(av, pb1, O[1][dn]);
            }
            __builtin_amdgcn_s_setprio(0);
        }
    }

    // --- l reduction: lanes {m, m+16, m+32, m+48} hold quad-partials of row m ---
#pragma unroll
    for (int mt = 0; mt < 2; ++mt) {
        float s = mt ? l1 : l0;
        s += __shfl_xor(s, 16);
        s += __shfl_xor(s, 32);
        const float inv = 1.f / s;
        const size_t orow = (tokbase + qr0 + mt * 16 + lrow) * INNER + h * DHEAD;
#pragma unroll
        for (int dn = 0; dn < 4; ++dn) {
            const f32x4 o = O[mt][dn];
            f16x4 ov;
            ov[0] = (_Float16)(o[0] * inv); ov[1] = (_Float16)(o[1] * inv);
            ov[2] = (_Float16)(o[2] * inv); ov[3] = (_Float16)(o[3] * inv);
            *(f16x4*)(out + orow + dn * 16 + quad * 4) = ov;
        }
    }
}

// ---------------------------------------------------------------------------
extern "C" void kernel_launch(void* const* d_in, const int* in_sizes, int n_in,
                              void* d_out, int out_size, void* d_ws, size_t ws_size,
                              hipStream_t stream) {
    const float* x         = (const float*)d_in[0];
    const float* W_qkv     = (const float*)d_in[1];
    const float* rel_table = (const float*)d_in[2];
    const float* W_out     = (const float*)d_in[3];
    const float* b_out     = (const float*)d_in[4];

    _Float16* x_h   = (_Float16*)d_ws;                        // 8,388,608
    _Float16* Wq_t  = x_h + (size_t)BATCH * NTOK * INNER;     // 786,432
    _Float16* Wo_t  = Wq_t + (size_t)INNER * QKV_COLS;        // 262,144
    _Float16* qkv_h = Wo_t + (size_t)INNER * INNER;           // 25,165,824
    _Float16* att_h = qkv_h + (size_t)BATCH * NTOK * QKV_COLS;// 8,388,608
    _Float16* vt_g  = att_h + (size_t)BATCH * NTOK * INNER;   // 8,388,608

    const int M = BATCH * NTOK;  // 16384

    convert_inputs<<<(XV + WQ + WO + 255) / 256, 256, 0, stream>>>(
        x, W_qkv, W_out, x_h, Wq_t, Wo_t);

    // QKV GEMM; V col-blocks written directly in vt layout.
    gemm_f16<2><<<dim3(QKV_COLS / 128, M / 128), 256, 0, stream>>>(
        x_h, Wq_t, nullptr, qkv_h, vt_g, M, QKV_COLS, INNER);

    attn_f16_v7<<<dim3(NTOK / 256, HEADS, BATCH), 512, 0, stream>>>(
        qkv_h, vt_g, rel_table, att_h);

    gemm_f16<0><<<dim3(INNER / 128, M / 128), 256, 0, stream>>>(
        att_h, Wo_t, b_out, d_out, nullptr, M, INNER, INNER);
}